// Round 2
// baseline (496.285 us; speedup 1.0000x reference)
//
#include <hip/hip_runtime.h>
#include <hip/hip_bf16.h>
#include <math.h>

#define NN 50000
#define NE 800000

// ---------- bf16 pack/unpack helpers (internal storage only) ----------
__device__ __forceinline__ unsigned short f2bf(float f) {
    union { float f; unsigned int i; } v; v.f = f;
    unsigned int x = v.i;
    unsigned int r = (x >> 16) & 1u;          // round-to-nearest-even
    x += 0x7fffu + r;
    return (unsigned short)(x >> 16);
}
__device__ __forceinline__ void un2(unsigned int u, float& a, float& b) {
    union { unsigned int i; float f; } x, y;
    x.i = u << 16; y.i = u & 0xffff0000u;
    a = x.f; b = y.f;
}

// ---------- CSR build ----------
__global__ void k_deg(const int* __restrict__ ei, int* __restrict__ deg) {
    int i = blockIdx.x * 256 + threadIdx.x;
    if (i < NE) atomicAdd(&deg[ei[NE + i]], 1);
}

__global__ __launch_bounds__(1024) void k_scan(const int* __restrict__ deg,
                                               int* __restrict__ offs,
                                               int* __restrict__ cursor) {
    __shared__ int tmp[1024];
    int tid = threadIdx.x;
    const int PER = (NN + 1023) / 1024;   // 49
    int lo = tid * PER;
    int hi = lo + PER; if (hi > NN) hi = NN;
    int sum = 0;
    for (int i = lo; i < hi; i++) sum += deg[i];
    tmp[tid] = sum;
    __syncthreads();
    for (int off = 1; off < 1024; off <<= 1) {
        int t = (tid >= off) ? tmp[tid - off] : 0;
        __syncthreads();
        tmp[tid] += t;
        __syncthreads();
    }
    int run = tmp[tid] - sum;             // exclusive prefix of this thread's range
    for (int i = lo; i < hi; i++) {
        int d = deg[i];
        offs[i] = run; cursor[i] = run;
        run += d;
    }
}

__global__ void k_scatter(const int* __restrict__ ei, int* __restrict__ cursor,
                          int* __restrict__ ssrc) {
    int i = blockIdx.x * 256 + threadIdx.x;
    if (i < NE) {
        int s = ei[i];
        int d = ei[NE + i];
        int pos = atomicAdd(&cursor[d], 1);
        ssrc[pos] = s;
    }
}

// ---------- Layer 1 GEMM: h1 = x @ W1 (fp32 in, bf16 out) + alpha scalars ----------
__global__ __launch_bounds__(256) void k_gemm1(
    const float* __restrict__ x,     // [NN,128] fp32
    const float* __restrict__ W1,    // [128,128] fp32
    const float* __restrict__ aS,    // [8,16] fp32
    const float* __restrict__ aD,    // [8,16] fp32
    unsigned short* __restrict__ h1, // [NN,128] bf16 out
    float* __restrict__ as1,         // [NN,8]
    float* __restrict__ ad1)         // [NN,8]
{
    __shared__ float Wl[128 * 128];  // 64 KB
    __shared__ float xl[16 * 129];   // padded
    __shared__ float aSf[128], aDf[128];
    int t = threadIdx.x;

    const float4* Wg = (const float4*)W1;
    float4* Wl4 = (float4*)Wl;
#pragma unroll
    for (int i = 0; i < 16; i++) Wl4[t + 256 * i] = Wg[t + 256 * i];
    if (t < 128) { aSf[t] = aS[t]; aDf[t] = aD[t]; }

    {   // stage 16 rows of x (grid is exactly NN/16)
        const float4* xg = (const float4*)(x + (size_t)blockIdx.x * 16 * 128);
#pragma unroll
        for (int i = 0; i < 2; i++) {
            float4 v = xg[t + 256 * i];
            int lin = (t + 256 * i) * 4;
            int rr = lin >> 7, cc = lin & 127;
            float* p = &xl[rr * 129 + cc];
            p[0] = v.x; p[1] = v.y; p[2] = v.z; p[3] = v.w;
        }
    }
    __syncthreads();

    int r = t >> 4, cg = t & 15, c0 = cg * 8;
    float acc[8];
#pragma unroll
    for (int i = 0; i < 8; i++) acc[i] = 0.f;
    const float* xrow = &xl[r * 129];
#pragma unroll 4
    for (int k = 0; k < 128; k++) {
        float xv = xrow[k];
        float4 wa = *(const float4*)&Wl[k * 128 + c0];
        float4 wb = *(const float4*)&Wl[k * 128 + c0 + 4];
        acc[0] += xv * wa.x; acc[1] += xv * wa.y; acc[2] += xv * wa.z; acc[3] += xv * wa.w;
        acc[4] += xv * wb.x; acc[5] += xv * wb.y; acc[6] += xv * wb.z; acc[7] += xv * wb.w;
    }

    size_t row = (size_t)blockIdx.x * 16 + r;
    uint4 o;
    o.x = (unsigned int)f2bf(acc[0]) | ((unsigned int)f2bf(acc[1]) << 16);
    o.y = (unsigned int)f2bf(acc[2]) | ((unsigned int)f2bf(acc[3]) << 16);
    o.z = (unsigned int)f2bf(acc[4]) | ((unsigned int)f2bf(acc[5]) << 16);
    o.w = (unsigned int)f2bf(acc[6]) | ((unsigned int)f2bf(acc[7]) << 16);
    *(uint4*)&((unsigned int*)h1)[row * 64 + cg * 4] = o;

    float asp = 0.f, adp = 0.f;
#pragma unroll
    for (int i = 0; i < 8; i++) { asp += acc[i] * aSf[c0 + i]; adp += acc[i] * aDf[c0 + i]; }
    asp += __shfl_xor(asp, 1);
    adp += __shfl_xor(adp, 1);
    if ((cg & 1) == 0) {
        int head = cg >> 1;
        as1[row * 8 + head] = asp;
        ad1[row * 8 + head] = adp;
    }
}

// ---------- Layer 1 aggregation: one wave per dst node ----------
__global__ __launch_bounds__(256) void k_agg1(
    const int* __restrict__ offs, const int* __restrict__ deg,
    const int* __restrict__ ssrc,
    const float* __restrict__ as1, const float* __restrict__ ad1,
    const unsigned short* __restrict__ h1, const float* __restrict__ b1,
    unsigned short* __restrict__ h2)
{
    int wave = threadIdx.x >> 6;
    int lane = threadIdx.x & 63;
    int node = blockIdx.x * 4 + wave;
    if (node >= NN) return;
    int start = offs[node], cnt = deg[node];

    // pass 1: denominators for 8 heads (lane = jg*8 + head)
    int hh = lane & 7, jg = lane >> 3;
    float adv_h = ad1[node * 8 + hh];
    float dpart = 0.f;
    for (int base = 0; base <= cnt; base += 8) {
        int j = base + jg;
        if (j <= cnt) {
            int s = (j < cnt) ? ssrc[start + j] : node;   // j==cnt -> self loop
            float e = as1[s * 8 + hh] + adv_h;
            e = (e > 0.f) ? e : 0.2f * e;
            dpart += __expf(e);
        }
    }
    dpart += __shfl_xor(dpart, 8);
    dpart += __shfl_xor(dpart, 16);
    dpart += __shfl_xor(dpart, 32);

    int myhead = lane >> 3;                 // pass 2: lane covers cols 2*lane, 2*lane+1
    float denom = __shfl(dpart, myhead);    // lane 'myhead' holds denom[myhead]
    float inv = 1.0f / denom;
    float adv = ad1[node * 8 + myhead];

    float acc0 = 0.f, acc1 = 0.f;
    const unsigned int* h1u = (const unsigned int*)h1;
    for (int j = 0; j <= cnt; j++) {
        int s = (j < cnt) ? ssrc[start + j] : node;
        float e = as1[s * 8 + myhead] + adv;
        e = (e > 0.f) ? e : 0.2f * e;
        float w = __expf(e) * inv;
        unsigned int u = h1u[s * 64 + lane];
        float f0, f1; un2(u, f0, f1);
        acc0 += w * f0;
        acc1 += w * f1;
    }

    float v0 = acc0 + b1[2 * lane];
    float v1 = acc1 + b1[2 * lane + 1];
    v0 = (v0 > 0.f) ? v0 : (__expf(v0) - 1.0f);   // ELU
    v1 = (v1 > 0.f) ? v1 : (__expf(v1) - 1.0f);
    unsigned int o = (unsigned int)f2bf(v0) | ((unsigned int)f2bf(v1) << 16);
    ((unsigned int*)h2)[node * 64 + lane] = o;
}

// ---------- Layer 2 GEMM: g2 = h2 @ W2 + alpha scalars ----------
__global__ __launch_bounds__(256) void k_gemm2(
    const unsigned short* __restrict__ h2,   // [NN,128] bf16
    const float* __restrict__ W2,            // [128,16] fp32
    const float* __restrict__ aS2,           // [16]
    const float* __restrict__ aD2,           // [16]
    float* __restrict__ g2,                  // [NN,16]
    float* __restrict__ as2, float* __restrict__ ad2)
{
    __shared__ float Wl[128 * 16];     // 8 KB
    __shared__ float xl[32 * 129];     // padded
    __shared__ float aSf[16], aDf[16];
    int t = threadIdx.x;

    for (int i = t; i < 2048; i += 256) Wl[i] = W2[i];
    if (t < 16) { aSf[t] = aS2[t]; aDf[t] = aD2[t]; }

    int rowbase = blockIdx.x * 32;
    for (int i = t; i < 2048; i += 256) {        // 32 rows * 64 uints
        int row = rowbase + (i >> 6);
        unsigned int u = (row < NN) ? ((const unsigned int*)h2)[(size_t)rowbase * 64 + i] : 0u;
        float a, b; un2(u, a, b);
        int lin = 2 * i;
        int rr = lin >> 7, kk = lin & 127;
        xl[rr * 129 + kk] = a;
        xl[rr * 129 + kk + 1] = b;
    }
    __syncthreads();

    int r = t >> 3, cp = t & 7;
    int row = rowbase + r;
    float a0 = 0.f, a1 = 0.f;
    const float* xrow = &xl[r * 129];
#pragma unroll 4
    for (int k = 0; k < 128; k++) {
        float xv = xrow[k];
        a0 += xv * Wl[k * 16 + 2 * cp];
        a1 += xv * Wl[k * 16 + 2 * cp + 1];
    }
    if (row < NN) ((float2*)g2)[(size_t)row * 8 + cp] = make_float2(a0, a1);

    float asp = a0 * aSf[2 * cp] + a1 * aSf[2 * cp + 1];
    float adp = a0 * aDf[2 * cp] + a1 * aDf[2 * cp + 1];
    asp += __shfl_xor(asp, 1); asp += __shfl_xor(asp, 2); asp += __shfl_xor(asp, 4);
    adp += __shfl_xor(adp, 1); adp += __shfl_xor(adp, 2); adp += __shfl_xor(adp, 4);
    if (cp == 0 && row < NN) { as2[row] = asp; ad2[row] = adp; }
}

// ---------- Layer 2 aggregation: one wave per dst node ----------
__global__ __launch_bounds__(256) void k_agg2(
    const int* __restrict__ offs, const int* __restrict__ deg,
    const int* __restrict__ ssrc,
    const float* __restrict__ as2, const float* __restrict__ ad2,
    const float* __restrict__ g2, const float* __restrict__ b2,
    float* __restrict__ out)
{
    int wave = threadIdx.x >> 6;
    int lane = threadIdx.x & 63;
    int node = blockIdx.x * 4 + wave;
    if (node >= NN) return;
    int start = offs[node], cnt = deg[node];
    float adv = ad2[node];

    float dpart = 0.f;
    for (int base = 0; base <= cnt; base += 64) {
        int j = base + lane;
        if (j <= cnt) {
            int s = (j < cnt) ? ssrc[start + j] : node;
            float e = as2[s] + adv;
            e = (e > 0.f) ? e : 0.2f * e;
            dpart += __expf(e);
        }
    }
#pragma unroll
    for (int m = 1; m < 64; m <<= 1) dpart += __shfl_xor(dpart, m);
    float inv = 1.0f / dpart;

    int col = lane & 15, jg = lane >> 4;
    float acc = 0.f;
    for (int base = 0; base <= cnt; base += 4) {
        int j = base + jg;
        if (j <= cnt) {
            int s = (j < cnt) ? ssrc[start + j] : node;
            float e = as2[s] + adv;
            e = (e > 0.f) ? e : 0.2f * e;
            float w = __expf(e) * inv;
            acc += w * g2[(size_t)s * 16 + col];
        }
    }
    acc += __shfl_xor(acc, 16);
    acc += __shfl_xor(acc, 32);
    if (lane < 16) {
        out[(size_t)node * 16 + col] = acc + b2[col];
    }
}

// ---------- launch ----------
extern "C" void kernel_launch(void* const* d_in, const int* in_sizes, int n_in,
                              void* d_out, int out_size, void* d_ws, size_t ws_size,
                              hipStream_t stream) {
    const float* x   = (const float*)d_in[0];
    const int*   ei  = (const int*)d_in[1];
    const float* W1  = (const float*)d_in[2];
    const float* aS1 = (const float*)d_in[3];
    const float* aD1 = (const float*)d_in[4];
    const float* b1  = (const float*)d_in[5];
    const float* W2  = (const float*)d_in[6];
    const float* aS2 = (const float*)d_in[7];
    const float* aD2 = (const float*)d_in[8];
    const float* b2  = (const float*)d_in[9];

    char* ws = (char*)d_ws;
    size_t off = 0;
    auto alloc = [&](size_t bytes) { void* p = ws + off; off += (bytes + 255) & ~(size_t)255; return p; };

    unsigned short* h1 = (unsigned short*)alloc((size_t)NN * 128 * 2);  // bf16
    unsigned short* h2 = (unsigned short*)alloc((size_t)NN * 128 * 2);  // bf16
    float* as1 = (float*)alloc((size_t)NN * 8 * 4);
    float* ad1 = (float*)alloc((size_t)NN * 8 * 4);
    float* g2  = (float*)alloc((size_t)NN * 16 * 4);
    float* as2 = (float*)alloc((size_t)NN * 4);
    float* ad2 = (float*)alloc((size_t)NN * 4);
    int* deg    = (int*)alloc((size_t)NN * 4);
    int* offs   = (int*)alloc((size_t)NN * 4);
    int* cursor = (int*)alloc((size_t)NN * 4);
    int* ssrc   = (int*)alloc((size_t)NE * 4);

    hipMemsetAsync(deg, 0, (size_t)NN * 4, stream);
    k_deg<<<(NE + 255) / 256, 256, 0, stream>>>(ei, deg);
    k_scan<<<1, 1024, 0, stream>>>(deg, offs, cursor);
    k_scatter<<<(NE + 255) / 256, 256, 0, stream>>>(ei, cursor, ssrc);

    k_gemm1<<<NN / 16, 256, 0, stream>>>(x, W1, aS1, aD1, h1, as1, ad1);
    k_agg1<<<(NN + 3) / 4, 256, 0, stream>>>(offs, deg, ssrc, as1, ad1, h1, b1, h2);
    k_gemm2<<<(NN + 31) / 32, 256, 0, stream>>>(h2, W2, aS2, aD2, g2, as2, ad2);
    k_agg2<<<(NN + 3) / 4, 256, 0, stream>>>(offs, deg, ssrc, as2, ad2, g2, b2,
                                             (float*)d_out);
}

// Round 3
// 388.103 us; speedup vs baseline: 1.2787x; 1.2787x over previous
//
#include <hip/hip_runtime.h>
#include <hip/hip_bf16.h>
#include <math.h>

#define NN 50000
#define NE 800000
#define NB1 196   // (NN+255)/256

// ---------- bf16 pack/unpack helpers (internal storage only) ----------
__device__ __forceinline__ unsigned short f2bf(float f) {
    union { float f; unsigned int i; } v; v.f = f;
    unsigned int x = v.i;
    unsigned int r = (x >> 16) & 1u;          // round-to-nearest-even
    x += 0x7fffu + r;
    return (unsigned short)(x >> 16);
}
__device__ __forceinline__ void un2(unsigned int u, float& a, float& b) {
    union { unsigned int i; float f; } x, y;
    x.i = u << 16; y.i = u & 0xffff0000u;
    a = x.f; b = y.f;
}

// ---------- CSR build ----------
__global__ void k_deg(const int* __restrict__ ei, int* __restrict__ deg) {
    int i = blockIdx.x * 256 + threadIdx.x;
    if (i < NE) atomicAdd(&deg[ei[NE + i]], 1);
}

// phase 1: per-block sums of deg
__global__ __launch_bounds__(256) void k_bsum(const int* __restrict__ deg,
                                              int* __restrict__ bsum) {
    __shared__ int red[4];
    int t = threadIdx.x;
    int i = blockIdx.x * 256 + t;
    int v = (i < NN) ? deg[i] : 0;
#pragma unroll
    for (int m = 1; m < 64; m <<= 1) v += __shfl_xor(v, m);
    if ((t & 63) == 0) red[t >> 6] = v;
    __syncthreads();
    if (t == 0) bsum[blockIdx.x] = red[0] + red[1] + red[2] + red[3];
}

// phase 2: exclusive scan of NB1 block sums (one small block)
__global__ __launch_bounds__(256) void k_bscan(const int* __restrict__ bsum,
                                               int* __restrict__ bpre) {
    __shared__ int tmp[256];
    int t = threadIdx.x;
    int v = (t < NB1) ? bsum[t] : 0;
    tmp[t] = v;
    __syncthreads();
    for (int off = 1; off < 256; off <<= 1) {
        int u = (t >= off) ? tmp[t - off] : 0;
        __syncthreads();
        tmp[t] += u;
        __syncthreads();
    }
    if (t < NB1) bpre[t] = tmp[t] - v;   // exclusive
}

// phase 3: block-local scan + global prefix -> offs/cursor
__global__ __launch_bounds__(256) void k_apply(const int* __restrict__ deg,
                                               const int* __restrict__ bpre,
                                               int* __restrict__ offs,
                                               int* __restrict__ cursor) {
    __shared__ int tmp[256];
    int t = threadIdx.x;
    int i = blockIdx.x * 256 + t;
    int v = (i < NN) ? deg[i] : 0;
    tmp[t] = v;
    __syncthreads();
    for (int off = 1; off < 256; off <<= 1) {
        int u = (t >= off) ? tmp[t - off] : 0;
        __syncthreads();
        tmp[t] += u;
        __syncthreads();
    }
    if (i < NN) {
        int o = bpre[blockIdx.x] + tmp[t] - v;
        offs[i] = o;
        cursor[i] = o;
    }
}

__global__ void k_scatter(const int* __restrict__ ei, int* __restrict__ cursor,
                          int* __restrict__ ssrc) {
    int i = blockIdx.x * 256 + threadIdx.x;
    if (i < NE) {
        int s = ei[i];
        int d = ei[NE + i];
        int pos = atomicAdd(&cursor[d], 1);
        ssrc[pos] = s;
    }
}

// ---------- Layer 1 GEMM: h1 = x @ W1 (fp32 in, bf16 out) + alpha scalars ----------
__global__ __launch_bounds__(256) void k_gemm1(
    const float* __restrict__ x,     // [NN,128] fp32
    const float* __restrict__ W1,    // [128,128] fp32
    const float* __restrict__ aS,    // [8,16] fp32
    const float* __restrict__ aD,    // [8,16] fp32
    unsigned short* __restrict__ h1, // [NN,128] bf16 out
    float* __restrict__ as1,         // [NN,8]
    float* __restrict__ ad1)         // [NN,8]
{
    __shared__ float Wl[128 * 128];  // 64 KB
    __shared__ float xl[16 * 129];   // padded
    __shared__ float aSf[128], aDf[128];
    int t = threadIdx.x;

    const float4* Wg = (const float4*)W1;
    float4* Wl4 = (float4*)Wl;
#pragma unroll
    for (int i = 0; i < 16; i++) Wl4[t + 256 * i] = Wg[t + 256 * i];
    if (t < 128) { aSf[t] = aS[t]; aDf[t] = aD[t]; }

    {   // stage 16 rows of x (grid is exactly NN/16)
        const float4* xg = (const float4*)(x + (size_t)blockIdx.x * 16 * 128);
#pragma unroll
        for (int i = 0; i < 2; i++) {
            float4 v = xg[t + 256 * i];
            int lin = (t + 256 * i) * 4;
            int rr = lin >> 7, cc = lin & 127;
            float* p = &xl[rr * 129 + cc];
            p[0] = v.x; p[1] = v.y; p[2] = v.z; p[3] = v.w;
        }
    }
    __syncthreads();

    int r = t >> 4, cg = t & 15, c0 = cg * 8;
    float acc[8];
#pragma unroll
    for (int i = 0; i < 8; i++) acc[i] = 0.f;
    const float* xrow = &xl[r * 129];
#pragma unroll 4
    for (int k = 0; k < 128; k++) {
        float xv = xrow[k];
        float4 wa = *(const float4*)&Wl[k * 128 + c0];
        float4 wb = *(const float4*)&Wl[k * 128 + c0 + 4];
        acc[0] += xv * wa.x; acc[1] += xv * wa.y; acc[2] += xv * wa.z; acc[3] += xv * wa.w;
        acc[4] += xv * wb.x; acc[5] += xv * wb.y; acc[6] += xv * wb.z; acc[7] += xv * wb.w;
    }

    size_t row = (size_t)blockIdx.x * 16 + r;
    uint4 o;
    o.x = (unsigned int)f2bf(acc[0]) | ((unsigned int)f2bf(acc[1]) << 16);
    o.y = (unsigned int)f2bf(acc[2]) | ((unsigned int)f2bf(acc[3]) << 16);
    o.z = (unsigned int)f2bf(acc[4]) | ((unsigned int)f2bf(acc[5]) << 16);
    o.w = (unsigned int)f2bf(acc[6]) | ((unsigned int)f2bf(acc[7]) << 16);
    *(uint4*)&((unsigned int*)h1)[row * 64 + cg * 4] = o;

    float asp = 0.f, adp = 0.f;
#pragma unroll
    for (int i = 0; i < 8; i++) { asp += acc[i] * aSf[c0 + i]; adp += acc[i] * aDf[c0 + i]; }
    asp += __shfl_xor(asp, 1);
    adp += __shfl_xor(adp, 1);
    if ((cg & 1) == 0) {
        int head = cg >> 1;
        as1[row * 8 + head] = asp;
        ad1[row * 8 + head] = adp;
    }
}

// ---------- Layer 1 aggregation: single-pass softmax, one wave per dst node ----------
__global__ __launch_bounds__(256) void k_agg1(
    const int* __restrict__ offs, const int* __restrict__ deg,
    const int* __restrict__ ssrc,
    const float* __restrict__ as1, const float* __restrict__ ad1,
    const unsigned short* __restrict__ h1, const float* __restrict__ b1,
    unsigned short* __restrict__ h2)
{
    int wave = threadIdx.x >> 6;
    int lane = threadIdx.x & 63;
    int node = blockIdx.x * 4 + wave;
    if (node >= NN) return;
    int start = offs[node], cnt = deg[node];

    int myhead = lane >> 3;                  // lane covers cols 2*lane, 2*lane+1
    float adv = ad1[node * 8 + myhead];

    // single pass: unnormalized numerator + denominator (exp(e) bounded ~55, no overflow)
    float acc0 = 0.f, acc1 = 0.f, dsum = 0.f;
    const unsigned int* h1u = (const unsigned int*)h1;
    for (int base = 0; base <= cnt; base += 4) {   // 4-edge unroll for MLP
        int sv[4]; float wv[4];
#pragma unroll
        for (int q = 0; q < 4; q++) {
            int j = base + q;
            sv[q] = (j < cnt) ? ssrc[start + j] : node;
        }
#pragma unroll
        for (int q = 0; q < 4; q++) {
            int j = base + q;
            if (j <= cnt) {
                float e = as1[sv[q] * 8 + myhead] + adv;
                e = (e > 0.f) ? e : 0.2f * e;
                wv[q] = __expf(e);
            } else wv[q] = 0.f;
        }
#pragma unroll
        for (int q = 0; q < 4; q++) {
            int j = base + q;
            if (j <= cnt) {
                unsigned int u = h1u[(size_t)sv[q] * 64 + lane];
                float f0, f1; un2(u, f0, f1);
                acc0 += wv[q] * f0;
                acc1 += wv[q] * f1;
                dsum += wv[q];
            }
        }
    }

    float inv = 1.0f / dsum;
    float v0 = acc0 * inv + b1[2 * lane];
    float v1 = acc1 * inv + b1[2 * lane + 1];
    v0 = (v0 > 0.f) ? v0 : (__expf(v0) - 1.0f);   // ELU
    v1 = (v1 > 0.f) ? v1 : (__expf(v1) - 1.0f);
    unsigned int o = (unsigned int)f2bf(v0) | ((unsigned int)f2bf(v1) << 16);
    ((unsigned int*)h2)[node * 64 + lane] = o;
}

// ---------- Layer 2 GEMM: g2 = h2 @ W2 + alpha scalars ----------
__global__ __launch_bounds__(256) void k_gemm2(
    const unsigned short* __restrict__ h2,   // [NN,128] bf16
    const float* __restrict__ W2,            // [128,16] fp32
    const float* __restrict__ aS2,           // [16]
    const float* __restrict__ aD2,           // [16]
    float* __restrict__ g2,                  // [NN,16]
    float* __restrict__ as2, float* __restrict__ ad2)
{
    __shared__ float Wl[128 * 16];     // 8 KB
    __shared__ float xl[32 * 129];     // padded
    __shared__ float aSf[16], aDf[16];
    int t = threadIdx.x;

    for (int i = t; i < 2048; i += 256) Wl[i] = W2[i];
    if (t < 16) { aSf[t] = aS2[t]; aDf[t] = aD2[t]; }

    int rowbase = blockIdx.x * 32;
    for (int i = t; i < 2048; i += 256) {        // 32 rows * 64 uints
        int row = rowbase + (i >> 6);
        unsigned int u = (row < NN) ? ((const unsigned int*)h2)[(size_t)rowbase * 64 + i] : 0u;
        float a, b; un2(u, a, b);
        int lin = 2 * i;
        int rr = lin >> 7, kk = lin & 127;
        xl[rr * 129 + kk] = a;
        xl[rr * 129 + kk + 1] = b;
    }
    __syncthreads();

    int r = t >> 3, cp = t & 7;
    int row = rowbase + r;
    float a0 = 0.f, a1 = 0.f;
    const float* xrow = &xl[r * 129];
#pragma unroll 4
    for (int k = 0; k < 128; k++) {
        float xv = xrow[k];
        a0 += xv * Wl[k * 16 + 2 * cp];
        a1 += xv * Wl[k * 16 + 2 * cp + 1];
    }
    if (row < NN) ((float2*)g2)[(size_t)row * 8 + cp] = make_float2(a0, a1);

    float asp = a0 * aSf[2 * cp] + a1 * aSf[2 * cp + 1];
    float adp = a0 * aDf[2 * cp] + a1 * aDf[2 * cp + 1];
    asp += __shfl_xor(asp, 1); asp += __shfl_xor(asp, 2); asp += __shfl_xor(asp, 4);
    adp += __shfl_xor(adp, 1); adp += __shfl_xor(adp, 2); adp += __shfl_xor(adp, 4);
    if (cp == 0 && row < NN) { as2[row] = asp; ad2[row] = adp; }
}

// ---------- Layer 2 aggregation: single-pass softmax, one wave per dst node ----------
__global__ __launch_bounds__(256) void k_agg2(
    const int* __restrict__ offs, const int* __restrict__ deg,
    const int* __restrict__ ssrc,
    const float* __restrict__ as2, const float* __restrict__ ad2,
    const float* __restrict__ g2, const float* __restrict__ b2,
    float* __restrict__ out)
{
    int wave = threadIdx.x >> 6;
    int lane = threadIdx.x & 63;
    int node = blockIdx.x * 4 + wave;
    if (node >= NN) return;
    int start = offs[node], cnt = deg[node];
    float adv = ad2[node];

    int col = lane & 15, jg = lane >> 4;     // 4 parallel edge groups
    float acc = 0.f, dsum = 0.f;
    for (int base = 0; base <= cnt; base += 4) {
        int j = base + jg;
        if (j <= cnt) {
            int s = (j < cnt) ? ssrc[start + j] : node;
            float e = as2[s] + adv;
            e = (e > 0.f) ? e : 0.2f * e;
            float w = __expf(e);
            acc += w * g2[(size_t)s * 16 + col];
            dsum += w;
        }
    }
    // reduce numerator and denominator across the 4 jg groups
    acc  += __shfl_xor(acc, 16);  acc  += __shfl_xor(acc, 32);
    dsum += __shfl_xor(dsum, 16); dsum += __shfl_xor(dsum, 32);
    if (lane < 16) {
        out[(size_t)node * 16 + col] = acc / dsum + b2[col];
    }
}

// ---------- launch ----------
extern "C" void kernel_launch(void* const* d_in, const int* in_sizes, int n_in,
                              void* d_out, int out_size, void* d_ws, size_t ws_size,
                              hipStream_t stream) {
    const float* x   = (const float*)d_in[0];
    const int*   ei  = (const int*)d_in[1];
    const float* W1  = (const float*)d_in[2];
    const float* aS1 = (const float*)d_in[3];
    const float* aD1 = (const float*)d_in[4];
    const float* b1  = (const float*)d_in[5];
    const float* W2  = (const float*)d_in[6];
    const float* aS2 = (const float*)d_in[7];
    const float* aD2 = (const float*)d_in[8];
    const float* b2  = (const float*)d_in[9];

    char* ws = (char*)d_ws;
    size_t off = 0;
    auto alloc = [&](size_t bytes) { void* p = ws + off; off += (bytes + 255) & ~(size_t)255; return p; };

    unsigned short* h1 = (unsigned short*)alloc((size_t)NN * 128 * 2);  // bf16
    unsigned short* h2 = (unsigned short*)alloc((size_t)NN * 128 * 2);  // bf16
    float* as1 = (float*)alloc((size_t)NN * 8 * 4);
    float* ad1 = (float*)alloc((size_t)NN * 8 * 4);
    float* g2  = (float*)alloc((size_t)NN * 16 * 4);
    float* as2 = (float*)alloc((size_t)NN * 4);
    float* ad2 = (float*)alloc((size_t)NN * 4);
    int* deg    = (int*)alloc((size_t)NN * 4);
    int* offs   = (int*)alloc((size_t)NN * 4);
    int* cursor = (int*)alloc((size_t)NN * 4);
    int* ssrc   = (int*)alloc((size_t)NE * 4);
    int* bsum   = (int*)alloc((size_t)NB1 * 4);
    int* bpre   = (int*)alloc((size_t)NB1 * 4);

    hipMemsetAsync(deg, 0, (size_t)NN * 4, stream);
    k_deg<<<(NE + 255) / 256, 256, 0, stream>>>(ei, deg);
    k_bsum<<<NB1, 256, 0, stream>>>(deg, bsum);
    k_bscan<<<1, 256, 0, stream>>>(bsum, bpre);
    k_apply<<<NB1, 256, 0, stream>>>(deg, bpre, offs, cursor);
    k_scatter<<<(NE + 255) / 256, 256, 0, stream>>>(ei, cursor, ssrc);

    k_gemm1<<<NN / 16, 256, 0, stream>>>(x, W1, aS1, aD1, h1, as1, ad1);
    k_agg1<<<(NN + 3) / 4, 256, 0, stream>>>(offs, deg, ssrc, as1, ad1, h1, b1, h2);
    k_gemm2<<<(NN + 31) / 32, 256, 0, stream>>>(h2, W2, aS2, aD2, g2, as2, ad2);
    k_agg2<<<(NN + 3) / 4, 256, 0, stream>>>(offs, deg, ssrc, as2, ad2, g2, b2,
                                             (float*)d_out);
}

// Round 4
// 327.694 us; speedup vs baseline: 1.5145x; 1.1843x over previous
//
#include <hip/hip_runtime.h>
#include <hip/hip_bf16.h>
#include <math.h>

#define NN 50000
#define NE 800000
#define NB1 196   // (NN+255)/256

// ---------- bf16 pack/unpack helpers (internal storage only) ----------
__device__ __forceinline__ unsigned short f2bf(float f) {
    union { float f; unsigned int i; } v; v.f = f;
    unsigned int x = v.i;
    unsigned int r = (x >> 16) & 1u;          // round-to-nearest-even
    x += 0x7fffu + r;
    return (unsigned short)(x >> 16);
}
__device__ __forceinline__ void un2(unsigned int u, float& a, float& b) {
    union { unsigned int i; float f; } x, y;
    x.i = u << 16; y.i = u & 0xffff0000u;
    a = x.f; b = y.f;
}

// ---------- CSR build ----------
__global__ void k_deg(const int* __restrict__ ei, int* __restrict__ deg) {
    int i = blockIdx.x * 256 + threadIdx.x;
    if (i < NE) atomicAdd(&deg[ei[NE + i]], 1);
}

__global__ __launch_bounds__(256) void k_bsum(const int* __restrict__ deg,
                                              int* __restrict__ bsum) {
    __shared__ int red[4];
    int t = threadIdx.x;
    int i = blockIdx.x * 256 + t;
    int v = (i < NN) ? deg[i] : 0;
#pragma unroll
    for (int m = 1; m < 64; m <<= 1) v += __shfl_xor(v, m);
    if ((t & 63) == 0) red[t >> 6] = v;
    __syncthreads();
    if (t == 0) bsum[blockIdx.x] = red[0] + red[1] + red[2] + red[3];
}

__global__ __launch_bounds__(256) void k_bscan(const int* __restrict__ bsum,
                                               int* __restrict__ bpre) {
    __shared__ int tmp[256];
    int t = threadIdx.x;
    int v = (t < NB1) ? bsum[t] : 0;
    tmp[t] = v;
    __syncthreads();
    for (int off = 1; off < 256; off <<= 1) {
        int u = (t >= off) ? tmp[t - off] : 0;
        __syncthreads();
        tmp[t] += u;
        __syncthreads();
    }
    if (t < NB1) bpre[t] = tmp[t] - v;   // exclusive
}

__global__ __launch_bounds__(256) void k_apply(const int* __restrict__ deg,
                                               const int* __restrict__ bpre,
                                               int* __restrict__ offs,
                                               int* __restrict__ cursor) {
    __shared__ int tmp[256];
    int t = threadIdx.x;
    int i = blockIdx.x * 256 + t;
    int v = (i < NN) ? deg[i] : 0;
    tmp[t] = v;
    __syncthreads();
    for (int off = 1; off < 256; off <<= 1) {
        int u = (t >= off) ? tmp[t - off] : 0;
        __syncthreads();
        tmp[t] += u;
        __syncthreads();
    }
    if (i < NN) {
        int o = bpre[blockIdx.x] + tmp[t] - v;
        offs[i] = o;
        cursor[i] = o;
    }
}

__global__ void k_scatter(const int* __restrict__ ei, int* __restrict__ cursor,
                          int* __restrict__ ssrc) {
    int i = blockIdx.x * 256 + threadIdx.x;
    if (i < NE) {
        int s = ei[i];
        int d = ei[NE + i];
        int pos = atomicAdd(&cursor[d], 1);
        ssrc[pos] = s;
    }
}

// ---------- Layer 1 GEMM: h1 = x @ W1 (fp32 in, bf16 out) + alpha scalars ----------
__global__ __launch_bounds__(256) void k_gemm1(
    const float* __restrict__ x,     // [NN,128] fp32
    const float* __restrict__ W1,    // [128,128] fp32
    const float* __restrict__ aS,    // [8,16] fp32
    const float* __restrict__ aD,    // [8,16] fp32
    unsigned short* __restrict__ h1, // [NN,128] bf16 out
    float* __restrict__ as1,         // [NN,8]
    float* __restrict__ ad1)         // [NN,8]
{
    __shared__ float Wl[128 * 128];  // 64 KB
    __shared__ float xl[16 * 129];   // padded
    __shared__ float aSf[128], aDf[128];
    int t = threadIdx.x;

    const float4* Wg = (const float4*)W1;
    float4* Wl4 = (float4*)Wl;
#pragma unroll
    for (int i = 0; i < 16; i++) Wl4[t + 256 * i] = Wg[t + 256 * i];
    if (t < 128) { aSf[t] = aS[t]; aDf[t] = aD[t]; }

    {   // stage 16 rows of x (grid is exactly NN/16)
        const float4* xg = (const float4*)(x + (size_t)blockIdx.x * 16 * 128);
#pragma unroll
        for (int i = 0; i < 2; i++) {
            float4 v = xg[t + 256 * i];
            int lin = (t + 256 * i) * 4;
            int rr = lin >> 7, cc = lin & 127;
            float* p = &xl[rr * 129 + cc];
            p[0] = v.x; p[1] = v.y; p[2] = v.z; p[3] = v.w;
        }
    }
    __syncthreads();

    int r = t >> 4, cg = t & 15, c0 = cg * 8;
    float acc[8];
#pragma unroll
    for (int i = 0; i < 8; i++) acc[i] = 0.f;
    const float* xrow = &xl[r * 129];
#pragma unroll 4
    for (int k = 0; k < 128; k++) {
        float xv = xrow[k];
        float4 wa = *(const float4*)&Wl[k * 128 + c0];
        float4 wb = *(const float4*)&Wl[k * 128 + c0 + 4];
        acc[0] += xv * wa.x; acc[1] += xv * wa.y; acc[2] += xv * wa.z; acc[3] += xv * wa.w;
        acc[4] += xv * wb.x; acc[5] += xv * wb.y; acc[6] += xv * wb.z; acc[7] += xv * wb.w;
    }

    size_t row = (size_t)blockIdx.x * 16 + r;
    uint4 o;
    o.x = (unsigned int)f2bf(acc[0]) | ((unsigned int)f2bf(acc[1]) << 16);
    o.y = (unsigned int)f2bf(acc[2]) | ((unsigned int)f2bf(acc[3]) << 16);
    o.z = (unsigned int)f2bf(acc[4]) | ((unsigned int)f2bf(acc[5]) << 16);
    o.w = (unsigned int)f2bf(acc[6]) | ((unsigned int)f2bf(acc[7]) << 16);
    *(uint4*)&((unsigned int*)h1)[row * 64 + cg * 4] = o;

    float asp = 0.f, adp = 0.f;
#pragma unroll
    for (int i = 0; i < 8; i++) { asp += acc[i] * aSf[c0 + i]; adp += acc[i] * aDf[c0 + i]; }
    asp += __shfl_xor(asp, 1);
    adp += __shfl_xor(adp, 1);
    if ((cg & 1) == 0) {
        int head = cg >> 1;
        as1[row * 8 + head] = asp;
        ad1[row * 8 + head] = adp;
    }
}

// ---------- Layer 1 aggregation: one wave per node, 4 edges in flight via uint4 rows ----------
// lane = jg*16 + li : jg in [0,4) = edge group, li in [0,16) = 16B chunk of the 256B h1 row.
// li covers cols [li*8, li*8+8) -> head = li>>1.
__global__ __launch_bounds__(256) void k_agg1(
    const int* __restrict__ offs, const int* __restrict__ deg,
    const int* __restrict__ ssrc,
    const float* __restrict__ as1, const float* __restrict__ ad1,
    const unsigned short* __restrict__ h1, const float* __restrict__ b1,
    unsigned short* __restrict__ h2)
{
    int wave = threadIdx.x >> 6;
    int lane = threadIdx.x & 63;
    int node = blockIdx.x * 4 + wave;
    if (node >= NN) return;
    int start = offs[node], cnt = deg[node];

    int li = lane & 15, jg = lane >> 4;
    int head = li >> 1;
    float adv = ad1[node * 8 + head];

    const uint4* h1u4 = (const uint4*)h1;
    float acc[8];
#pragma unroll
    for (int i = 0; i < 8; i++) acc[i] = 0.f;
    float dsum = 0.f;

    for (int base = 0; base <= cnt; base += 8) {    // 2 x 4 edges in flight
#pragma unroll
        for (int u = 0; u < 2; u++) {
            int j = base + u * 4 + jg;
            if (j <= cnt) {
                int s = (j < cnt) ? ssrc[start + j] : node;   // j==cnt -> self loop
                float e = as1[s * 8 + head] + adv;
                e = (e > 0.f) ? e : 0.2f * e;
                float w = __expf(e);
                uint4 hv = h1u4[(size_t)s * 16 + li];
                float f0, f1, f2, f3, f4, f5, f6, f7;
                un2(hv.x, f0, f1); un2(hv.y, f2, f3);
                un2(hv.z, f4, f5); un2(hv.w, f6, f7);
                acc[0] += w * f0; acc[1] += w * f1; acc[2] += w * f2; acc[3] += w * f3;
                acc[4] += w * f4; acc[5] += w * f5; acc[6] += w * f6; acc[7] += w * f7;
                if ((li & 1) == 0) dsum += w;       // count each (item,head) once
            }
        }
    }

    // reduce across the 4 edge groups (lanes with same li)
#pragma unroll
    for (int i = 0; i < 8; i++) {
        acc[i] += __shfl_xor(acc[i], 16);
        acc[i] += __shfl_xor(acc[i], 32);
    }
    dsum += __shfl_xor(dsum, 16);
    dsum += __shfl_xor(dsum, 32);
    dsum += __shfl_xor(dsum, 1);    // broadcast even-li denom to odd li

    if (jg == 0) {
        float inv = 1.0f / dsum;
        int c0 = li * 8;
        float v[8];
#pragma unroll
        for (int i = 0; i < 8; i++) {
            float vv = acc[i] * inv + b1[c0 + i];
            v[i] = (vv > 0.f) ? vv : (__expf(vv) - 1.0f);   // ELU
        }
        uint4 o;
        o.x = (unsigned int)f2bf(v[0]) | ((unsigned int)f2bf(v[1]) << 16);
        o.y = (unsigned int)f2bf(v[2]) | ((unsigned int)f2bf(v[3]) << 16);
        o.z = (unsigned int)f2bf(v[4]) | ((unsigned int)f2bf(v[5]) << 16);
        o.w = (unsigned int)f2bf(v[6]) | ((unsigned int)f2bf(v[7]) << 16);
        ((uint4*)h2)[(size_t)node * 16 + li] = o;
    }
}

// ---------- Layer 2 GEMM: g2 = h2 @ W2 + alpha scalars ----------
__global__ __launch_bounds__(256) void k_gemm2(
    const unsigned short* __restrict__ h2,   // [NN,128] bf16
    const float* __restrict__ W2,            // [128,16] fp32
    const float* __restrict__ aS2,           // [16]
    const float* __restrict__ aD2,           // [16]
    float* __restrict__ g2,                  // [NN,16]
    float* __restrict__ as2, float* __restrict__ ad2)
{
    __shared__ float Wl[128 * 16];     // 8 KB
    __shared__ float xl[32 * 129];     // padded
    __shared__ float aSf[16], aDf[16];
    int t = threadIdx.x;

    for (int i = t; i < 2048; i += 256) Wl[i] = W2[i];
    if (t < 16) { aSf[t] = aS2[t]; aDf[t] = aD2[t]; }

    int rowbase = blockIdx.x * 32;
    for (int i = t; i < 2048; i += 256) {        // 32 rows * 64 uints
        int row = rowbase + (i >> 6);
        unsigned int u = (row < NN) ? ((const unsigned int*)h2)[(size_t)rowbase * 64 + i] : 0u;
        float a, b; un2(u, a, b);
        int lin = 2 * i;
        int rr = lin >> 7, kk = lin & 127;
        xl[rr * 129 + kk] = a;
        xl[rr * 129 + kk + 1] = b;
    }
    __syncthreads();

    int r = t >> 3, cp = t & 7;
    int row = rowbase + r;
    float a0 = 0.f, a1 = 0.f;
    const float* xrow = &xl[r * 129];
#pragma unroll 4
    for (int k = 0; k < 128; k++) {
        float xv = xrow[k];
        a0 += xv * Wl[k * 16 + 2 * cp];
        a1 += xv * Wl[k * 16 + 2 * cp + 1];
    }
    if (row < NN) ((float2*)g2)[(size_t)row * 8 + cp] = make_float2(a0, a1);

    float asp = a0 * aSf[2 * cp] + a1 * aSf[2 * cp + 1];
    float adp = a0 * aDf[2 * cp] + a1 * aDf[2 * cp + 1];
    asp += __shfl_xor(asp, 1); asp += __shfl_xor(asp, 2); asp += __shfl_xor(asp, 4);
    adp += __shfl_xor(adp, 1); adp += __shfl_xor(adp, 2); adp += __shfl_xor(adp, 4);
    if (cp == 0 && row < NN) { as2[row] = asp; ad2[row] = adp; }
}

// ---------- Layer 2 aggregation: one wave per node, 16 edges in flight via float4 ----------
// lane = jg*4 + li4 : jg in [0,16) = edge group, li4 in [0,4) = float4 chunk of g2 row.
__global__ __launch_bounds__(256) void k_agg2(
    const int* __restrict__ offs, const int* __restrict__ deg,
    const int* __restrict__ ssrc,
    const float* __restrict__ as2, const float* __restrict__ ad2,
    const float* __restrict__ g2, const float* __restrict__ b2,
    float* __restrict__ out)
{
    int wave = threadIdx.x >> 6;
    int lane = threadIdx.x & 63;
    int node = blockIdx.x * 4 + wave;
    if (node >= NN) return;
    int start = offs[node], cnt = deg[node];
    float adv = ad2[node];

    int li4 = lane & 3, jg = lane >> 2;
    const float4* g2f4 = (const float4*)g2;

    float a0 = 0.f, a1 = 0.f, a2 = 0.f, a3 = 0.f, dsum = 0.f;
    for (int base = 0; base <= cnt; base += 16) {
        int j = base + jg;
        if (j <= cnt) {
            int s = (j < cnt) ? ssrc[start + j] : node;
            float e = as2[s] + adv;
            e = (e > 0.f) ? e : 0.2f * e;
            float w = __expf(e);
            float4 g = g2f4[(size_t)s * 4 + li4];
            a0 += w * g.x; a1 += w * g.y; a2 += w * g.z; a3 += w * g.w;
            if (li4 == 0) dsum += w;
        }
    }
#pragma unroll
    for (int m = 4; m < 64; m <<= 1) {
        a0 += __shfl_xor(a0, m); a1 += __shfl_xor(a1, m);
        a2 += __shfl_xor(a2, m); a3 += __shfl_xor(a3, m);
        dsum += __shfl_xor(dsum, m);
    }
    dsum += __shfl_xor(dsum, 1);
    dsum += __shfl_xor(dsum, 2);   // broadcast denom to all li4

    if (jg == 0) {
        float inv = 1.0f / dsum;
        const float4* b2f4 = (const float4*)b2;
        float4 bb = b2f4[li4];
        float4 o = make_float4(a0 * inv + bb.x, a1 * inv + bb.y,
                               a2 * inv + bb.z, a3 * inv + bb.w);
        ((float4*)out)[(size_t)node * 4 + li4] = o;
    }
}

// ---------- launch ----------
extern "C" void kernel_launch(void* const* d_in, const int* in_sizes, int n_in,
                              void* d_out, int out_size, void* d_ws, size_t ws_size,
                              hipStream_t stream) {
    const float* x   = (const float*)d_in[0];
    const int*   ei  = (const int*)d_in[1];
    const float* W1  = (const float*)d_in[2];
    const float* aS1 = (const float*)d_in[3];
    const float* aD1 = (const float*)d_in[4];
    const float* b1  = (const float*)d_in[5];
    const float* W2  = (const float*)d_in[6];
    const float* aS2 = (const float*)d_in[7];
    const float* aD2 = (const float*)d_in[8];
    const float* b2  = (const float*)d_in[9];

    char* ws = (char*)d_ws;
    size_t off = 0;
    auto alloc = [&](size_t bytes) { void* p = ws + off; off += (bytes + 255) & ~(size_t)255; return p; };

    unsigned short* h1 = (unsigned short*)alloc((size_t)NN * 128 * 2);  // bf16
    unsigned short* h2 = (unsigned short*)alloc((size_t)NN * 128 * 2);  // bf16
    float* as1 = (float*)alloc((size_t)NN * 8 * 4);
    float* ad1 = (float*)alloc((size_t)NN * 8 * 4);
    float* g2  = (float*)alloc((size_t)NN * 16 * 4);
    float* as2 = (float*)alloc((size_t)NN * 4);
    float* ad2 = (float*)alloc((size_t)NN * 4);
    int* deg    = (int*)alloc((size_t)NN * 4);
    int* offs   = (int*)alloc((size_t)NN * 4);
    int* cursor = (int*)alloc((size_t)NN * 4);
    int* ssrc   = (int*)alloc((size_t)NE * 4);
    int* bsum   = (int*)alloc((size_t)NB1 * 4);
    int* bpre   = (int*)alloc((size_t)NB1 * 4);

    hipMemsetAsync(deg, 0, (size_t)NN * 4, stream);
    k_deg<<<(NE + 255) / 256, 256, 0, stream>>>(ei, deg);
    k_bsum<<<NB1, 256, 0, stream>>>(deg, bsum);
    k_bscan<<<1, 256, 0, stream>>>(bsum, bpre);
    k_apply<<<NB1, 256, 0, stream>>>(deg, bpre, offs, cursor);
    k_scatter<<<(NE + 255) / 256, 256, 0, stream>>>(ei, cursor, ssrc);

    k_gemm1<<<NN / 16, 256, 0, stream>>>(x, W1, aS1, aD1, h1, as1, ad1);
    k_agg1<<<(NN + 3) / 4, 256, 0, stream>>>(offs, deg, ssrc, as1, ad1, h1, b1, h2);
    k_gemm2<<<(NN + 31) / 32, 256, 0, stream>>>(h2, W2, aS2, aD2, g2, as2, ad2);
    k_agg2<<<(NN + 3) / 4, 256, 0, stream>>>(offs, deg, ssrc, as2, ad2, g2, b2,
                                             (float*)d_out);
}

// Round 5
// 283.328 us; speedup vs baseline: 1.7516x; 1.1566x over previous
//
#include <hip/hip_runtime.h>
#include <hip/hip_bf16.h>
#include <math.h>

#define NN 50000
#define NE 800000
#define NB1 196   // (NN+255)/256
#define APITCH 136  // padded bf16 row pitch for gemm1 A-tile

typedef short bf16x8 __attribute__((ext_vector_type(8)));
typedef float f32x4  __attribute__((ext_vector_type(4)));

// ---------- bf16 pack/unpack helpers (internal storage only) ----------
__device__ __forceinline__ unsigned short f2bf(float f) {
    union { float f; unsigned int i; } v; v.f = f;
    unsigned int x = v.i;
    unsigned int r = (x >> 16) & 1u;          // round-to-nearest-even
    x += 0x7fffu + r;
    return (unsigned short)(x >> 16);
}
__device__ __forceinline__ void un2(unsigned int u, float& a, float& b) {
    union { unsigned int i; float f; } x, y;
    x.i = u << 16; y.i = u & 0xffff0000u;
    a = x.f; b = y.f;
}

// ---------- CSR build ----------
__global__ void k_deg(const int* __restrict__ ei, int* __restrict__ deg) {
    int i = blockIdx.x * 256 + threadIdx.x;
    if (i < NE) atomicAdd(&deg[ei[NE + i]], 1);
}

__global__ __launch_bounds__(256) void k_bsum(const int* __restrict__ deg,
                                              int* __restrict__ bsum) {
    __shared__ int red[4];
    int t = threadIdx.x;
    int i = blockIdx.x * 256 + t;
    int v = (i < NN) ? deg[i] : 0;
#pragma unroll
    for (int m = 1; m < 64; m <<= 1) v += __shfl_xor(v, m);
    if ((t & 63) == 0) red[t >> 6] = v;
    __syncthreads();
    if (t == 0) bsum[blockIdx.x] = red[0] + red[1] + red[2] + red[3];
}

__global__ __launch_bounds__(256) void k_bscan(const int* __restrict__ bsum,
                                               int* __restrict__ bpre) {
    __shared__ int tmp[256];
    int t = threadIdx.x;
    int v = (t < NB1) ? bsum[t] : 0;
    tmp[t] = v;
    __syncthreads();
    for (int off = 1; off < 256; off <<= 1) {
        int u = (t >= off) ? tmp[t - off] : 0;
        __syncthreads();
        tmp[t] += u;
        __syncthreads();
    }
    if (t < NB1) bpre[t] = tmp[t] - v;   // exclusive
}

__global__ __launch_bounds__(256) void k_apply(const int* __restrict__ deg,
                                               const int* __restrict__ bpre,
                                               int* __restrict__ offs,
                                               int* __restrict__ cursor) {
    __shared__ int tmp[256];
    int t = threadIdx.x;
    int i = blockIdx.x * 256 + t;
    int v = (i < NN) ? deg[i] : 0;
    tmp[t] = v;
    __syncthreads();
    for (int off = 1; off < 256; off <<= 1) {
        int u = (t >= off) ? tmp[t - off] : 0;
        __syncthreads();
        tmp[t] += u;
        __syncthreads();
    }
    if (i < NN) {
        int o = bpre[blockIdx.x] + tmp[t] - v;
        offs[i] = o;
        cursor[i] = o;
    }
}

__global__ void k_scatter(const int* __restrict__ ei, int* __restrict__ cursor,
                          int* __restrict__ ssrc) {
    int i = blockIdx.x * 256 + threadIdx.x;
    if (i < NE) {
        int s = ei[i];
        int d = ei[NE + i];
        int pos = atomicAdd(&cursor[d], 1);
        ssrc[pos] = s;
    }
}

// ---------- W1 -> B-fragment-major bf16 swizzle (once, 8 blocks) ----------
// layout: fragment f = nt*256 + kc*64 + lane holds B[k= kc*32+(lane>>4)*8+j][n= nt*16+(lane&15)], j=0..7
__global__ __launch_bounds__(256) void k_swizw(const float* __restrict__ W1,
                                               uint4* __restrict__ W1s) {
    int f = blockIdx.x * 256 + threadIdx.x;   // [0,2048)
    int nt = f >> 8, kc = (f >> 6) & 3, l = f & 63;
    int n  = nt * 16 + (l & 15);
    int k0 = kc * 32 + (l >> 4) * 8;
    unsigned int p[4];
#pragma unroll
    for (int jj = 0; jj < 4; jj++) {
        float v0 = W1[(k0 + 2 * jj) * 128 + n];
        float v1 = W1[(k0 + 2 * jj + 1) * 128 + n];
        p[jj] = (unsigned int)f2bf(v0) | ((unsigned int)f2bf(v1) << 16);
    }
    W1s[f] = make_uint4(p[0], p[1], p[2], p[3]);
}

// ---------- Layer 1 GEMM via MFMA: h1 = bf16(x) @ bf16(W1), fp32 acc ----------
// block = 256 thr (4 waves), tile = 64 rows x 128 cols. wave w covers cols [w*32,w*32+32).
__global__ __launch_bounds__(256) void k_gemm1(
    const float* __restrict__ x,      // [NN,128] fp32
    const uint4* __restrict__ W1s,    // swizzled bf16 fragments
    const float* __restrict__ aS,     // [8,16]
    const float* __restrict__ aD,     // [8,16]
    unsigned short* __restrict__ h1,  // [NN,128] bf16 out
    float* __restrict__ as1,          // [NN,8]
    float* __restrict__ ad1)          // [NN,8]
{
    __shared__ unsigned short Alds[64 * APITCH];   // 17408 B
    int t = threadIdx.x;
    int w = t >> 6, l = t & 63;
    int rowbase = blockIdx.x * 64;

    // stage A: 64x128 fp32 -> bf16 LDS (coalesced float4 loads)
    {
        const float4* xg = (const float4*)(x + (size_t)rowbase * 128);
#pragma unroll
        for (int i = 0; i < 8; i++) {
            int idx = t + 256 * i;             // float4 id [0,2048)
            int r = idx >> 5, c = (idx & 31) * 4;
            float4 v = make_float4(0.f, 0.f, 0.f, 0.f);
            if (rowbase + r < NN) v = xg[idx];
            unsigned int p0 = (unsigned int)f2bf(v.x) | ((unsigned int)f2bf(v.y) << 16);
            unsigned int p1 = (unsigned int)f2bf(v.z) | ((unsigned int)f2bf(v.w) << 16);
            *(uint2*)&Alds[r * APITCH + c] = make_uint2(p0, p1);
        }
    }

    // load B fragments for this wave's two n-tiles (heads 2w, 2w+1)
    union BU { uint4 u; bf16x8 v; };
    BU b[2][4];
#pragma unroll
    for (int j = 0; j < 2; j++) {
        int nt = 2 * w + j;
#pragma unroll
        for (int kc = 0; kc < 4; kc++)
            b[j][kc].u = W1s[(nt * 4 + kc) * 64 + l];
    }
    __syncthreads();

    f32x4 acc[4][2];
#pragma unroll
    for (int mt = 0; mt < 4; mt++)
#pragma unroll
        for (int j = 0; j < 2; j++) acc[mt][j] = (f32x4){0.f, 0.f, 0.f, 0.f};

    int mrow = l & 15, quad = l >> 4;
#pragma unroll
    for (int kc = 0; kc < 4; kc++) {
#pragma unroll
        for (int mt = 0; mt < 4; mt++) {
            bf16x8 a = *(const bf16x8*)&Alds[(mt * 16 + mrow) * APITCH + kc * 32 + quad * 8];
            acc[mt][0] = __builtin_amdgcn_mfma_f32_16x16x32_bf16(a, b[0][kc].v, acc[mt][0], 0, 0, 0);
            acc[mt][1] = __builtin_amdgcn_mfma_f32_16x16x32_bf16(a, b[1][kc].v, acc[mt][1], 0, 0, 0);
        }
    }

    // alpha scalars: n-tile == head; reduce 16 cols (lanes of a quad) per row
#pragma unroll
    for (int j = 0; j < 2; j++) {
        int head = 2 * w + j;
        float aSv = aS[head * 16 + mrow];
        float aDv = aD[head * 16 + mrow];
#pragma unroll
        for (int mt = 0; mt < 4; mt++) {
#pragma unroll
            for (int reg = 0; reg < 4; reg++) {
                float s = acc[mt][j][reg] * aSv;
                float d = acc[mt][j][reg] * aDv;
                s += __shfl_xor(s, 1); s += __shfl_xor(s, 2);
                s += __shfl_xor(s, 4); s += __shfl_xor(s, 8);
                d += __shfl_xor(d, 1); d += __shfl_xor(d, 2);
                d += __shfl_xor(d, 4); d += __shfl_xor(d, 8);
                if (mrow == 0) {
                    int grow = rowbase + mt * 16 + quad * 4 + reg;
                    if (grow < NN) {
                        as1[grow * 8 + head] = s;
                        ad1[grow * 8 + head] = d;
                    }
                }
            }
        }
    }

    // h1 store: transpose C-layout through LDS, then coalesced uint4 stores
    __syncthreads();   // A reads done; reuse Alds
#pragma unroll
    for (int mt = 0; mt < 4; mt++)
#pragma unroll
        for (int j = 0; j < 2; j++) {
            int col = w * 32 + j * 16 + mrow;
#pragma unroll
            for (int reg = 0; reg < 4; reg++) {
                int r = mt * 16 + quad * 4 + reg;
                Alds[r * APITCH + col] = f2bf(acc[mt][j][reg]);
            }
        }
    __syncthreads();
    uint4* hg = (uint4*)h1;   // 16 uint4 per 128-col row
#pragma unroll
    for (int i = 0; i < 4; i++) {
        int idx = t + 256 * i;           // uint4 id [0,1024)
        int r = idx >> 4, ci = idx & 15;
        if (rowbase + r < NN)
            hg[(size_t)(rowbase + r) * 16 + ci] = *(const uint4*)&Alds[r * APITCH + ci * 8];
    }
}

// ---------- Layer 1 aggregation: one wave per node, 4 edges in flight via uint4 rows ----------
__global__ __launch_bounds__(256) void k_agg1(
    const int* __restrict__ offs, const int* __restrict__ deg,
    const int* __restrict__ ssrc,
    const float* __restrict__ as1, const float* __restrict__ ad1,
    const unsigned short* __restrict__ h1, const float* __restrict__ b1,
    unsigned short* __restrict__ h2)
{
    int wave = threadIdx.x >> 6;
    int lane = threadIdx.x & 63;
    int node = blockIdx.x * 4 + wave;
    if (node >= NN) return;
    int start = offs[node], cnt = deg[node];

    int li = lane & 15, jg = lane >> 4;
    int head = li >> 1;
    float adv = ad1[node * 8 + head];

    const uint4* h1u4 = (const uint4*)h1;
    float acc[8];
#pragma unroll
    for (int i = 0; i < 8; i++) acc[i] = 0.f;
    float dsum = 0.f;

    for (int base = 0; base <= cnt; base += 8) {    // 2 x 4 edges in flight
#pragma unroll
        for (int u = 0; u < 2; u++) {
            int j = base + u * 4 + jg;
            if (j <= cnt) {
                int s = (j < cnt) ? ssrc[start + j] : node;   // j==cnt -> self loop
                float e = as1[s * 8 + head] + adv;
                e = (e > 0.f) ? e : 0.2f * e;
                float w = __expf(e);
                uint4 hv = h1u4[(size_t)s * 16 + li];
                float f0, f1, f2, f3, f4, f5, f6, f7;
                un2(hv.x, f0, f1); un2(hv.y, f2, f3);
                un2(hv.z, f4, f5); un2(hv.w, f6, f7);
                acc[0] += w * f0; acc[1] += w * f1; acc[2] += w * f2; acc[3] += w * f3;
                acc[4] += w * f4; acc[5] += w * f5; acc[6] += w * f6; acc[7] += w * f7;
                if ((li & 1) == 0) dsum += w;
            }
        }
    }

#pragma unroll
    for (int i = 0; i < 8; i++) {
        acc[i] += __shfl_xor(acc[i], 16);
        acc[i] += __shfl_xor(acc[i], 32);
    }
    dsum += __shfl_xor(dsum, 16);
    dsum += __shfl_xor(dsum, 32);
    dsum += __shfl_xor(dsum, 1);

    if (jg == 0) {
        float inv = 1.0f / dsum;
        int c0 = li * 8;
        float v[8];
#pragma unroll
        for (int i = 0; i < 8; i++) {
            float vv = acc[i] * inv + b1[c0 + i];
            v[i] = (vv > 0.f) ? vv : (__expf(vv) - 1.0f);   // ELU
        }
        uint4 o;
        o.x = (unsigned int)f2bf(v[0]) | ((unsigned int)f2bf(v[1]) << 16);
        o.y = (unsigned int)f2bf(v[2]) | ((unsigned int)f2bf(v[3]) << 16);
        o.z = (unsigned int)f2bf(v[4]) | ((unsigned int)f2bf(v[5]) << 16);
        o.w = (unsigned int)f2bf(v[6]) | ((unsigned int)f2bf(v[7]) << 16);
        ((uint4*)h2)[(size_t)node * 16 + li] = o;
    }
}

// ---------- Layer 2 GEMM: g2 = h2 @ W2 + alpha scalars ----------
__global__ __launch_bounds__(256) void k_gemm2(
    const unsigned short* __restrict__ h2,   // [NN,128] bf16
    const float* __restrict__ W2,            // [128,16] fp32
    const float* __restrict__ aS2,           // [16]
    const float* __restrict__ aD2,           // [16]
    float* __restrict__ g2,                  // [NN,16]
    float* __restrict__ as2, float* __restrict__ ad2)
{
    __shared__ float Wl[128 * 16];     // 8 KB
    __shared__ float xl[32 * 129];     // padded
    __shared__ float aSf[16], aDf[16];
    int t = threadIdx.x;

    for (int i = t; i < 2048; i += 256) Wl[i] = W2[i];
    if (t < 16) { aSf[t] = aS2[t]; aDf[t] = aD2[t]; }

    int rowbase = blockIdx.x * 32;
    for (int i = t; i < 2048; i += 256) {        // 32 rows * 64 uints
        int row = rowbase + (i >> 6);
        unsigned int u = (row < NN) ? ((const unsigned int*)h2)[(size_t)rowbase * 64 + i] : 0u;
        float a, b; un2(u, a, b);
        int lin = 2 * i;
        int rr = lin >> 7, kk = lin & 127;
        xl[rr * 129 + kk] = a;
        xl[rr * 129 + kk + 1] = b;
    }
    __syncthreads();

    int r = t >> 3, cp = t & 7;
    int row = rowbase + r;
    float a0 = 0.f, a1 = 0.f;
    const float* xrow = &xl[r * 129];
#pragma unroll 4
    for (int k = 0; k < 128; k++) {
        float xv = xrow[k];
        a0 += xv * Wl[k * 16 + 2 * cp];
        a1 += xv * Wl[k * 16 + 2 * cp + 1];
    }
    if (row < NN) ((float2*)g2)[(size_t)row * 8 + cp] = make_float2(a0, a1);

    float asp = a0 * aSf[2 * cp] + a1 * aSf[2 * cp + 1];
    float adp = a0 * aDf[2 * cp] + a1 * aDf[2 * cp + 1];
    asp += __shfl_xor(asp, 1); asp += __shfl_xor(asp, 2); asp += __shfl_xor(asp, 4);
    adp += __shfl_xor(adp, 1); adp += __shfl_xor(adp, 2); adp += __shfl_xor(adp, 4);
    if (cp == 0 && row < NN) { as2[row] = asp; ad2[row] = adp; }
}

// ---------- Layer 2 aggregation: one wave per node, 16 edges in flight via float4 ----------
__global__ __launch_bounds__(256) void k_agg2(
    const int* __restrict__ offs, const int* __restrict__ deg,
    const int* __restrict__ ssrc,
    const float* __restrict__ as2, const float* __restrict__ ad2,
    const float* __restrict__ g2, const float* __restrict__ b2,
    float* __restrict__ out)
{
    int wave = threadIdx.x >> 6;
    int lane = threadIdx.x & 63;
    int node = blockIdx.x * 4 + wave;
    if (node >= NN) return;
    int start = offs[node], cnt = deg[node];
    float adv = ad2[node];

    int li4 = lane & 3, jg = lane >> 2;
    const float4* g2f4 = (const float4*)g2;

    float a0 = 0.f, a1 = 0.f, a2 = 0.f, a3 = 0.f, dsum = 0.f;
    for (int base = 0; base <= cnt; base += 16) {
        int j = base + jg;
        if (j <= cnt) {
            int s = (j < cnt) ? ssrc[start + j] : node;
            float e = as2[s] + adv;
            e = (e > 0.f) ? e : 0.2f * e;
            float w = __expf(e);
            float4 g = g2f4[(size_t)s * 4 + li4];
            a0 += w * g.x; a1 += w * g.y; a2 += w * g.z; a3 += w * g.w;
            if (li4 == 0) dsum += w;
        }
    }
#pragma unroll
    for (int m = 4; m < 64; m <<= 1) {
        a0 += __shfl_xor(a0, m); a1 += __shfl_xor(a1, m);
        a2 += __shfl_xor(a2, m); a3 += __shfl_xor(a3, m);
        dsum += __shfl_xor(dsum, m);
    }
    dsum += __shfl_xor(dsum, 1);
    dsum += __shfl_xor(dsum, 2);   // broadcast denom to all li4

    if (jg == 0) {
        float inv = 1.0f / dsum;
        const float4* b2f4 = (const float4*)b2;
        float4 bb = b2f4[li4];
        float4 o = make_float4(a0 * inv + bb.x, a1 * inv + bb.y,
                               a2 * inv + bb.z, a3 * inv + bb.w);
        ((float4*)out)[(size_t)node * 4 + li4] = o;
    }
}

// ---------- launch ----------
extern "C" void kernel_launch(void* const* d_in, const int* in_sizes, int n_in,
                              void* d_out, int out_size, void* d_ws, size_t ws_size,
                              hipStream_t stream) {
    const float* x   = (const float*)d_in[0];
    const int*   ei  = (const int*)d_in[1];
    const float* W1  = (const float*)d_in[2];
    const float* aS1 = (const float*)d_in[3];
    const float* aD1 = (const float*)d_in[4];
    const float* b1  = (const float*)d_in[5];
    const float* W2  = (const float*)d_in[6];
    const float* aS2 = (const float*)d_in[7];
    const float* aD2 = (const float*)d_in[8];
    const float* b2  = (const float*)d_in[9];

    char* ws = (char*)d_ws;
    size_t off = 0;
    auto alloc = [&](size_t bytes) { void* p = ws + off; off += (bytes + 255) & ~(size_t)255; return p; };

    unsigned short* h1 = (unsigned short*)alloc((size_t)NN * 128 * 2);  // bf16
    unsigned short* h2 = (unsigned short*)alloc((size_t)NN * 128 * 2);  // bf16
    float* as1 = (float*)alloc((size_t)NN * 8 * 4);
    float* ad1 = (float*)alloc((size_t)NN * 8 * 4);
    float* g2  = (float*)alloc((size_t)NN * 16 * 4);
    float* as2 = (float*)alloc((size_t)NN * 4);
    float* ad2 = (float*)alloc((size_t)NN * 4);
    int* deg    = (int*)alloc((size_t)NN * 4);
    int* offs   = (int*)alloc((size_t)NN * 4);
    int* cursor = (int*)alloc((size_t)NN * 4);
    int* ssrc   = (int*)alloc((size_t)NE * 4);
    int* bsum   = (int*)alloc((size_t)NB1 * 4);
    int* bpre   = (int*)alloc((size_t)NB1 * 4);
    uint4* W1s  = (uint4*)alloc((size_t)2048 * 16);   // swizzled bf16 W1

    hipMemsetAsync(deg, 0, (size_t)NN * 4, stream);
    k_deg<<<(NE + 255) / 256, 256, 0, stream>>>(ei, deg);
    k_bsum<<<NB1, 256, 0, stream>>>(deg, bsum);
    k_bscan<<<1, 256, 0, stream>>>(bsum, bpre);
    k_apply<<<NB1, 256, 0, stream>>>(deg, bpre, offs, cursor);
    k_scatter<<<(NE + 255) / 256, 256, 0, stream>>>(ei, cursor, ssrc);

    k_swizw<<<8, 256, 0, stream>>>(W1, W1s);
    k_gemm1<<<(NN + 63) / 64, 256, 0, stream>>>(x, W1s, aS1, aD1, h1, as1, ad1);
    k_agg1<<<(NN + 3) / 4, 256, 0, stream>>>(offs, deg, ssrc, as1, ad1, h1, b1, h2);
    k_gemm2<<<(NN + 31) / 32, 256, 0, stream>>>(h2, W2, aS2, aD2, g2, as2, ad2);
    k_agg2<<<(NN + 3) / 4, 256, 0, stream>>>(offs, deg, ssrc, as2, ad2, g2, b2,
                                             (float*)d_out);
}

// Round 6
// 227.540 us; speedup vs baseline: 2.1811x; 1.2452x over previous
//
#include <hip/hip_runtime.h>
#include <hip/hip_bf16.h>
#include <math.h>

#define NN 50000
#define NE 800000
#define NBK 196          // buckets = (NN+255)/256, bucket = dst>>8
#define CHUNK 8192
#define NCH ((NE + CHUNK - 1) / CHUNK)   // 98
#define APITCH 136       // padded bf16 row pitch for gemm1 A-tile

typedef short bf16x8 __attribute__((ext_vector_type(8)));
typedef float f32x4  __attribute__((ext_vector_type(4)));

// ---------- bf16 pack/unpack helpers (internal storage only) ----------
__device__ __forceinline__ unsigned short f2bf(float f) {
    union { float f; unsigned int i; } v; v.f = f;
    unsigned int x = v.i;
    unsigned int r = (x >> 16) & 1u;          // round-to-nearest-even
    x += 0x7fffu + r;
    return (unsigned short)(x >> 16);
}
__device__ __forceinline__ void un2(unsigned int u, float& a, float& b) {
    union { unsigned int i; float f; } x, y;
    x.i = u << 16; y.i = u & 0xffff0000u;
    a = x.f; b = y.f;
}

// ---------- CSR build: bucket-partitioned counting sort ----------
// 1) per-bucket histogram (LDS-staged, few global atomics)
__global__ __launch_bounds__(256) void k_bhist(const int* __restrict__ ei,
                                               int* __restrict__ bhist) {
    __shared__ int h[NBK];
    int t = threadIdx.x;
    if (t < NBK) h[t] = 0;
    __syncthreads();
    int cb = blockIdx.x * CHUNK;
#pragma unroll
    for (int k = 0; k < CHUNK / 256; k++) {
        int i = cb + k * 256 + t;
        if (i < NE) atomicAdd(&h[ei[NE + i] >> 8], 1);
    }
    __syncthreads();
    if (t < NBK && h[t]) atomicAdd(&bhist[t], h[t]);
}

// 2) scan bucket sizes -> bucket bases + working cursors
__global__ __launch_bounds__(256) void k_bkscan(const int* __restrict__ bhist,
                                                int* __restrict__ bbase,
                                                int* __restrict__ gcur) {
    __shared__ int tmp[256];
    int t = threadIdx.x;
    int v = (t < NBK) ? bhist[t] : 0;
    tmp[t] = v;
    __syncthreads();
    for (int off = 1; off < 256; off <<= 1) {
        int u = (t >= off) ? tmp[t - off] : 0;
        __syncthreads();
        tmp[t] += u;
        __syncthreads();
    }
    if (t < NBK) { int e = tmp[t] - v; bbase[t] = e; gcur[t] = e; }
}

// 3) binned scatter of packed (src | dst_low<<16) into bucket-contiguous runs
__global__ __launch_bounds__(256) void k_bin(const int* __restrict__ ei,
                                             int* __restrict__ gcur,
                                             unsigned int* __restrict__ packed) {
    __shared__ int h[NBK];
    __shared__ int bas[NBK];
    int t = threadIdx.x;
    if (t < NBK) h[t] = 0;
    __syncthreads();
    int cb = blockIdx.x * CHUNK;
#pragma unroll
    for (int k = 0; k < CHUNK / 256; k++) {
        int i = cb + k * 256 + t;
        if (i < NE) atomicAdd(&h[ei[NE + i] >> 8], 1);
    }
    __syncthreads();
    if (t < NBK) {
        int c = h[t];
        bas[t] = c ? atomicAdd(&gcur[t], c) : 0;
        h[t] = 0;
    }
    __syncthreads();
#pragma unroll
    for (int k = 0; k < CHUNK / 256; k++) {
        int i = cb + k * 256 + t;
        if (i < NE) {
            int s = ei[i], d = ei[NE + i];
            int b = d >> 8;
            int r = atomicAdd(&h[b], 1);
            packed[bas[b] + r] = (unsigned int)s | ((unsigned int)(d & 255) << 16);
        }
    }
}

// 4) per-bucket finalize: deg/offs coalesced, ssrc built in LDS, no global atomics
__global__ __launch_bounds__(256) void k_final(const unsigned int* __restrict__ packed,
                                               const int* __restrict__ bbase,
                                               int* __restrict__ deg,
                                               int* __restrict__ offs,
                                               int* __restrict__ ssrc) {
    __shared__ unsigned int pk[8192];   // 32 KB
    __shared__ int osl[8192];           // 32 KB
    __shared__ int cnt[256], pre[256], cur[256];
    int t = threadIdx.x, b = blockIdx.x;
    int start = bbase[b];
    int end = (b + 1 < NBK) ? bbase[b + 1] : NE;
    int n = end - start;
    for (int i = t; i < n; i += 256) pk[i] = packed[start + i];
    cnt[t] = 0;
    __syncthreads();
    for (int i = t; i < n; i += 256) atomicAdd(&cnt[(pk[i] >> 16) & 255], 1);
    __syncthreads();
    int v = cnt[t];
    pre[t] = v;
    __syncthreads();
    for (int off = 1; off < 256; off <<= 1) {
        int u = (t >= off) ? pre[t - off] : 0;
        __syncthreads();
        pre[t] += u;
        __syncthreads();
    }
    int excl = pre[t] - v;
    int dst = b * 256 + t;
    if (dst < NN) { deg[dst] = v; offs[dst] = start + excl; }
    cur[t] = excl;
    __syncthreads();
    for (int i = t; i < n; i += 256) {
        unsigned int p = pk[i];
        int r = atomicAdd(&cur[(p >> 16) & 255], 1);
        osl[r] = (int)(p & 0xffffu);
    }
    __syncthreads();
    for (int i = t; i < n; i += 256) ssrc[start + i] = osl[i];
}

// ---------- W1 -> B-fragment-major bf16 swizzle (once, 8 blocks) ----------
__global__ __launch_bounds__(256) void k_swizw(const float* __restrict__ W1,
                                               uint4* __restrict__ W1s) {
    int f = blockIdx.x * 256 + threadIdx.x;   // [0,2048)
    int nt = f >> 8, kc = (f >> 6) & 3, l = f & 63;
    int n  = nt * 16 + (l & 15);
    int k0 = kc * 32 + (l >> 4) * 8;
    unsigned int p[4];
#pragma unroll
    for (int jj = 0; jj < 4; jj++) {
        float v0 = W1[(k0 + 2 * jj) * 128 + n];
        float v1 = W1[(k0 + 2 * jj + 1) * 128 + n];
        p[jj] = (unsigned int)f2bf(v0) | ((unsigned int)f2bf(v1) << 16);
    }
    W1s[f] = make_uint4(p[0], p[1], p[2], p[3]);
}

// ---------- Layer 1 GEMM via MFMA ----------
__global__ __launch_bounds__(256) void k_gemm1(
    const float* __restrict__ x,      // [NN,128] fp32
    const uint4* __restrict__ W1s,    // swizzled bf16 fragments
    const float* __restrict__ aS,     // [8,16]
    const float* __restrict__ aD,     // [8,16]
    unsigned short* __restrict__ h1,  // [NN,128] bf16 out
    float* __restrict__ as1,          // [NN,8]
    float* __restrict__ ad1)          // [NN,8]
{
    __shared__ unsigned short Alds[64 * APITCH];   // 17408 B
    int t = threadIdx.x;
    int w = t >> 6, l = t & 63;
    int rowbase = blockIdx.x * 64;

    {
        const float4* xg = (const float4*)(x + (size_t)rowbase * 128);
#pragma unroll
        for (int i = 0; i < 8; i++) {
            int idx = t + 256 * i;             // float4 id [0,2048)
            int r = idx >> 5, c = (idx & 31) * 4;
            float4 v = make_float4(0.f, 0.f, 0.f, 0.f);
            if (rowbase + r < NN) v = xg[idx];
            unsigned int p0 = (unsigned int)f2bf(v.x) | ((unsigned int)f2bf(v.y) << 16);
            unsigned int p1 = (unsigned int)f2bf(v.z) | ((unsigned int)f2bf(v.w) << 16);
            *(uint2*)&Alds[r * APITCH + c] = make_uint2(p0, p1);
        }
    }

    union BU { uint4 u; bf16x8 v; };
    BU b[2][4];
#pragma unroll
    for (int j = 0; j < 2; j++) {
        int nt = 2 * w + j;
#pragma unroll
        for (int kc = 0; kc < 4; kc++)
            b[j][kc].u = W1s[(nt * 4 + kc) * 64 + l];
    }
    __syncthreads();

    f32x4 acc[4][2];
#pragma unroll
    for (int mt = 0; mt < 4; mt++)
#pragma unroll
        for (int j = 0; j < 2; j++) acc[mt][j] = (f32x4){0.f, 0.f, 0.f, 0.f};

    int mrow = l & 15, quad = l >> 4;
#pragma unroll
    for (int kc = 0; kc < 4; kc++) {
#pragma unroll
        for (int mt = 0; mt < 4; mt++) {
            bf16x8 a = *(const bf16x8*)&Alds[(mt * 16 + mrow) * APITCH + kc * 32 + quad * 8];
            acc[mt][0] = __builtin_amdgcn_mfma_f32_16x16x32_bf16(a, b[0][kc].v, acc[mt][0], 0, 0, 0);
            acc[mt][1] = __builtin_amdgcn_mfma_f32_16x16x32_bf16(a, b[1][kc].v, acc[mt][1], 0, 0, 0);
        }
    }

#pragma unroll
    for (int j = 0; j < 2; j++) {
        int head = 2 * w + j;
        float aSv = aS[head * 16 + mrow];
        float aDv = aD[head * 16 + mrow];
#pragma unroll
        for (int mt = 0; mt < 4; mt++) {
#pragma unroll
            for (int reg = 0; reg < 4; reg++) {
                float s = acc[mt][j][reg] * aSv;
                float d = acc[mt][j][reg] * aDv;
                s += __shfl_xor(s, 1); s += __shfl_xor(s, 2);
                s += __shfl_xor(s, 4); s += __shfl_xor(s, 8);
                d += __shfl_xor(d, 1); d += __shfl_xor(d, 2);
                d += __shfl_xor(d, 4); d += __shfl_xor(d, 8);
                if (mrow == 0) {
                    int grow = rowbase + mt * 16 + quad * 4 + reg;
                    if (grow < NN) {
                        as1[grow * 8 + head] = s;
                        ad1[grow * 8 + head] = d;
                    }
                }
            }
        }
    }

    __syncthreads();   // A reads done; reuse Alds for C transpose
#pragma unroll
    for (int mt = 0; mt < 4; mt++)
#pragma unroll
        for (int j = 0; j < 2; j++) {
            int col = w * 32 + j * 16 + mrow;
#pragma unroll
            for (int reg = 0; reg < 4; reg++) {
                int r = mt * 16 + quad * 4 + reg;
                Alds[r * APITCH + col] = f2bf(acc[mt][j][reg]);
            }
        }
    __syncthreads();
    uint4* hg = (uint4*)h1;   // 16 uint4 per 128-col row
#pragma unroll
    for (int i = 0; i < 4; i++) {
        int idx = t + 256 * i;           // uint4 id [0,1024)
        int r = idx >> 4, ci = idx & 15;
        if (rowbase + r < NN)
            hg[(size_t)(rowbase + r) * 16 + ci] = *(const uint4*)&Alds[r * APITCH + ci * 8];
    }
}

// ---------- Layer 1 aggregation: one wave per node, 16 edges in flight ----------
__global__ __launch_bounds__(256) void k_agg1(
    const int* __restrict__ offs, const int* __restrict__ deg,
    const int* __restrict__ ssrc,
    const float* __restrict__ as1, const float* __restrict__ ad1,
    const unsigned short* __restrict__ h1, const float* __restrict__ b1,
    unsigned short* __restrict__ h2)
{
    int wave = threadIdx.x >> 6;
    int lane = threadIdx.x & 63;
    int node = blockIdx.x * 4 + wave;
    if (node >= NN) return;
    int start = offs[node], cnt = deg[node];

    int li = lane & 15, jg = lane >> 4;
    int head = li >> 1;
    float adv = ad1[node * 8 + head];

    const uint4* h1u4 = (const uint4*)h1;
    float acc[8];
#pragma unroll
    for (int i = 0; i < 8; i++) acc[i] = 0.f;
    float dsum = 0.f;

    for (int base = 0; base <= cnt; base += 16) {    // 4 x 4 edges in flight
#pragma unroll
        for (int u = 0; u < 4; u++) {
            int j = base + u * 4 + jg;
            if (j <= cnt) {
                int s = (j < cnt) ? ssrc[start + j] : node;   // j==cnt -> self loop
                float e = as1[s * 8 + head] + adv;
                e = (e > 0.f) ? e : 0.2f * e;
                float w = __expf(e);
                uint4 hv = h1u4[(size_t)s * 16 + li];
                float f0, f1, f2, f3, f4, f5, f6, f7;
                un2(hv.x, f0, f1); un2(hv.y, f2, f3);
                un2(hv.z, f4, f5); un2(hv.w, f6, f7);
                acc[0] += w * f0; acc[1] += w * f1; acc[2] += w * f2; acc[3] += w * f3;
                acc[4] += w * f4; acc[5] += w * f5; acc[6] += w * f6; acc[7] += w * f7;
                if ((li & 1) == 0) dsum += w;
            }
        }
    }

#pragma unroll
    for (int i = 0; i < 8; i++) {
        acc[i] += __shfl_xor(acc[i], 16);
        acc[i] += __shfl_xor(acc[i], 32);
    }
    dsum += __shfl_xor(dsum, 16);
    dsum += __shfl_xor(dsum, 32);
    dsum += __shfl_xor(dsum, 1);

    if (jg == 0) {
        float inv = 1.0f / dsum;
        int c0 = li * 8;
        float v[8];
#pragma unroll
        for (int i = 0; i < 8; i++) {
            float vv = acc[i] * inv + b1[c0 + i];
            v[i] = (vv > 0.f) ? vv : (__expf(vv) - 1.0f);   // ELU
        }
        uint4 o;
        o.x = (unsigned int)f2bf(v[0]) | ((unsigned int)f2bf(v[1]) << 16);
        o.y = (unsigned int)f2bf(v[2]) | ((unsigned int)f2bf(v[3]) << 16);
        o.z = (unsigned int)f2bf(v[4]) | ((unsigned int)f2bf(v[5]) << 16);
        o.w = (unsigned int)f2bf(v[6]) | ((unsigned int)f2bf(v[7]) << 16);
        ((uint4*)h2)[(size_t)node * 16 + li] = o;
    }
}

// ---------- Layer 2 GEMM ----------
__global__ __launch_bounds__(256) void k_gemm2(
    const unsigned short* __restrict__ h2,   // [NN,128] bf16
    const float* __restrict__ W2,            // [128,16] fp32
    const float* __restrict__ aS2,           // [16]
    const float* __restrict__ aD2,           // [16]
    float* __restrict__ g2,                  // [NN,16]
    float* __restrict__ as2, float* __restrict__ ad2)
{
    __shared__ float Wl[128 * 16];     // 8 KB
    __shared__ float xl[32 * 129];     // padded
    __shared__ float aSf[16], aDf[16];
    int t = threadIdx.x;

    for (int i = t; i < 2048; i += 256) Wl[i] = W2[i];
    if (t < 16) { aSf[t] = aS2[t]; aDf[t] = aD2[t]; }

    int rowbase = blockIdx.x * 32;
    for (int i = t; i < 2048; i += 256) {        // 32 rows * 64 uints
        int row = rowbase + (i >> 6);
        unsigned int u = (row < NN) ? ((const unsigned int*)h2)[(size_t)rowbase * 64 + i] : 0u;
        float a, b; un2(u, a, b);
        int lin = 2 * i;
        int rr = lin >> 7, kk = lin & 127;
        xl[rr * 129 + kk] = a;
        xl[rr * 129 + kk + 1] = b;
    }
    __syncthreads();

    int r = t >> 3, cp = t & 7;
    int row = rowbase + r;
    float a0 = 0.f, a1 = 0.f;
    const float* xrow = &xl[r * 129];
#pragma unroll 4
    for (int k = 0; k < 128; k++) {
        float xv = xrow[k];
        a0 += xv * Wl[k * 16 + 2 * cp];
        a1 += xv * Wl[k * 16 + 2 * cp + 1];
    }
    if (row < NN) ((float2*)g2)[(size_t)row * 8 + cp] = make_float2(a0, a1);

    float asp = a0 * aSf[2 * cp] + a1 * aSf[2 * cp + 1];
    float adp = a0 * aDf[2 * cp] + a1 * aDf[2 * cp + 1];
    asp += __shfl_xor(asp, 1); asp += __shfl_xor(asp, 2); asp += __shfl_xor(asp, 4);
    adp += __shfl_xor(adp, 1); adp += __shfl_xor(adp, 2); adp += __shfl_xor(adp, 4);
    if (cp == 0 && row < NN) { as2[row] = asp; ad2[row] = adp; }
}

// ---------- Layer 2 aggregation ----------
__global__ __launch_bounds__(256) void k_agg2(
    const int* __restrict__ offs, const int* __restrict__ deg,
    const int* __restrict__ ssrc,
    const float* __restrict__ as2, const float* __restrict__ ad2,
    const float* __restrict__ g2, const float* __restrict__ b2,
    float* __restrict__ out)
{
    int wave = threadIdx.x >> 6;
    int lane = threadIdx.x & 63;
    int node = blockIdx.x * 4 + wave;
    if (node >= NN) return;
    int start = offs[node], cnt = deg[node];
    float adv = ad2[node];

    int li4 = lane & 3, jg = lane >> 2;
    const float4* g2f4 = (const float4*)g2;

    float a0 = 0.f, a1 = 0.f, a2 = 0.f, a3 = 0.f, dsum = 0.f;
    for (int base = 0; base <= cnt; base += 16) {
        int j = base + jg;
        if (j <= cnt) {
            int s = (j < cnt) ? ssrc[start + j] : node;
            float e = as2[s] + adv;
            e = (e > 0.f) ? e : 0.2f * e;
            float w = __expf(e);
            float4 g = g2f4[(size_t)s * 4 + li4];
            a0 += w * g.x; a1 += w * g.y; a2 += w * g.z; a3 += w * g.w;
            if (li4 == 0) dsum += w;
        }
    }
#pragma unroll
    for (int m = 4; m < 64; m <<= 1) {
        a0 += __shfl_xor(a0, m); a1 += __shfl_xor(a1, m);
        a2 += __shfl_xor(a2, m); a3 += __shfl_xor(a3, m);
        dsum += __shfl_xor(dsum, m);
    }
    dsum += __shfl_xor(dsum, 1);
    dsum += __shfl_xor(dsum, 2);   // broadcast denom to all li4

    if (jg == 0) {
        float inv = 1.0f / dsum;
        const float4* b2f4 = (const float4*)b2;
        float4 bb = b2f4[li4];
        float4 o = make_float4(a0 * inv + bb.x, a1 * inv + bb.y,
                               a2 * inv + bb.z, a3 * inv + bb.w);
        ((float4*)out)[(size_t)node * 4 + li4] = o;
    }
}

// ---------- launch ----------
extern "C" void kernel_launch(void* const* d_in, const int* in_sizes, int n_in,
                              void* d_out, int out_size, void* d_ws, size_t ws_size,
                              hipStream_t stream) {
    const float* x   = (const float*)d_in[0];
    const int*   ei  = (const int*)d_in[1];
    const float* W1  = (const float*)d_in[2];
    const float* aS1 = (const float*)d_in[3];
    const float* aD1 = (const float*)d_in[4];
    const float* b1  = (const float*)d_in[5];
    const float* W2  = (const float*)d_in[6];
    const float* aS2 = (const float*)d_in[7];
    const float* aD2 = (const float*)d_in[8];
    const float* b2  = (const float*)d_in[9];

    char* ws = (char*)d_ws;
    size_t off = 0;
    auto alloc = [&](size_t bytes) { void* p = ws + off; off += (bytes + 255) & ~(size_t)255; return p; };

    unsigned short* h1 = (unsigned short*)alloc((size_t)NN * 128 * 2);  // bf16
    unsigned short* h2 = (unsigned short*)alloc((size_t)NN * 128 * 2);  // bf16
    float* as1 = (float*)alloc((size_t)NN * 8 * 4);
    float* ad1 = (float*)alloc((size_t)NN * 8 * 4);
    float* g2  = (float*)alloc((size_t)NN * 16 * 4);
    float* as2 = (float*)alloc((size_t)NN * 4);
    float* ad2 = (float*)alloc((size_t)NN * 4);
    int* deg    = (int*)alloc((size_t)NN * 4);
    int* offs   = (int*)alloc((size_t)NN * 4);
    int* ssrc   = (int*)alloc((size_t)NE * 4);
    unsigned int* packed = (unsigned int*)alloc((size_t)NE * 4);
    int* bhist  = (int*)alloc((size_t)NBK * 4);
    int* bbase  = (int*)alloc((size_t)NBK * 4);
    int* gcur   = (int*)alloc((size_t)NBK * 4);
    uint4* W1s  = (uint4*)alloc((size_t)2048 * 16);   // swizzled bf16 W1

    hipMemsetAsync(bhist, 0, (size_t)NBK * 4, stream);
    k_bhist<<<NCH, 256, 0, stream>>>(ei, bhist);
    k_bkscan<<<1, 256, 0, stream>>>(bhist, bbase, gcur);
    k_bin<<<NCH, 256, 0, stream>>>(ei, gcur, packed);
    k_final<<<NBK, 256, 0, stream>>>(packed, bbase, deg, offs, ssrc);

    k_swizw<<<8, 256, 0, stream>>>(W1, W1s);
    k_gemm1<<<(NN + 63) / 64, 256, 0, stream>>>(x, W1s, aS1, aD1, h1, as1, ad1);
    k_agg1<<<(NN + 3) / 4, 256, 0, stream>>>(offs, deg, ssrc, as1, ad1, h1, b1, h2);
    k_gemm2<<<(NN + 31) / 32, 256, 0, stream>>>(h2, W2, aS2, aD2, g2, as2, ad2);
    k_agg2<<<(NN + 3) / 4, 256, 0, stream>>>(offs, deg, ssrc, as2, ad2, g2, b2,
                                             (float*)d_out);
}